// Round 4
// baseline (1421.525 us; speedup 1.0000x reference)
//
#include <hip/hip_runtime.h>

// FeatureAttentionLayer: B=32, W=128, K=128, E=256, fp32.
//   L[i][e] = sum_w x[b][w][i]*lin_w[e][w] + lin_b[e]
//   R[j][e] = sum_w x[b][w][j]*lin_w[e][128+w]
//   e[i][j] = 0.6(dL[i]+dR[j]) + sum_e 0.4a[e]|L+R| + bias   (LReLU identity)
//   att = softmax_j; out[b][w][i] = sigmoid(sum_j att[i][j]*x[b][w][j])
//
// ws: P[b][r][k] (r<256: L^T rows; r>=256: R^T rows), 2M floats;
//     a6d/a4d = DUPLICATED pair arrays (a,a) for packed-f32 ops.
// Round-4 changes: deep register rings (latency ~700cy to L3 was exposed),
// packed v_pk_fma_f32 via ext_vector(2), phase-2 via LDS-transposed x.

typedef float v2f __attribute__((ext_vector_type(2)));
typedef float v4f __attribute__((ext_vector_type(4)));

#define WS_A6D  2097152
#define WS_A4D  (2097152 + 512)

__device__ __forceinline__ v2f vlo(v4f v){ return __builtin_shufflevector(v,v,0,1); }
__device__ __forceinline__ v2f vhi(v4f v){ return __builtin_shufflevector(v,v,2,3); }
__device__ __forceinline__ v2f pfma(v2f a, v2f b, v2f c){ return __builtin_elementwise_fma(a,b,c); }
__device__ __forceinline__ v2f pabs(v2f s){ return __builtin_elementwise_max(s, -s); }

// ---------------- K1: projection GEMM, x-ring depth 3 ----------------
// grid (32 b, 8 rt), 256 thr; thread: 8 k x 4 r.
__global__ __launch_bounds__(256,1) void k_linear(
    const float* __restrict__ x, const float* __restrict__ lin_w,
    const float* __restrict__ lin_b, const float* __restrict__ a,
    float* __restrict__ ws)
{
    const int t = threadIdx.x;
    const int b = blockIdx.x, rt = blockIdx.y;

    if (b == 0 && rt == 0) {           // fold a -> duplicated (0.6a,0.6a),(0.4a,0.4a)
        float av = a[t];
        *(v2f*)&ws[WS_A6D + 2*t] = (v2f){0.6f*av, 0.6f*av};
        *(v2f*)&ws[WS_A4D + 2*t] = (v2f){0.4f*av, 0.4f*av};
    }

    const int kp = t & 15, ep = t >> 4;
    const int k0 = kp * 8;
    const int r0 = rt * 64 + ep * 4;
    const bool isL = (rt < 4);

    const float* xb    = x + b * 16384 + k0;
    const float* Abase = isL ? (lin_w + (size_t)r0 * 256)
                             : (lin_w + (size_t)(r0 - 256) * 256 + 128);

    float acc[4][8] = {};
    v4f xb0[3][4], xb1[3][4], wb[2][4];

#define K1_XLD(s, c) do {                                                   \
    _Pragma("unroll") for (int ww = 0; ww < 4; ++ww) {                      \
      xb0[s][ww] = *(const v4f*)(xb + ((c)*4 + ww) * 128);                  \
      xb1[s][ww] = *(const v4f*)(xb + ((c)*4 + ww) * 128 + 4); } } while(0)

#define K1_WLD(s, c) do {                                                   \
    _Pragma("unroll") for (int ee = 0; ee < 4; ++ee)                        \
      wb[s][ee] = *(const v4f*)(Abase + ee * 256 + (c)*4); } while(0)

#define K1_CP(sx, sw) do {                                                  \
    _Pragma("unroll") for (int ww = 0; ww < 4; ++ww)                        \
      _Pragma("unroll") for (int ee = 0; ee < 4; ++ee) {                    \
        const float wv = wb[sw][ee][ww];                                    \
        _Pragma("unroll") for (int kk = 0; kk < 4; ++kk) {                  \
          acc[ee][kk]   = fmaf(xb0[sx][ww][kk], wv, acc[ee][kk]);           \
          acc[ee][kk+4] = fmaf(xb1[sx][ww][kk], wv, acc[ee][kk+4]); } } } while(0)

    K1_XLD(0, 0); K1_XLD(1, 1); K1_WLD(0, 0);
    #pragma unroll
    for (int c = 0; c < 32; ++c) {
        if (c + 2 < 32) K1_XLD((c + 2) % 3, c + 2);
        if (c + 1 < 32) K1_WLD((c + 1) & 1, c + 1);
        K1_CP(c % 3, c & 1);
    }

    #pragma unroll
    for (int ee = 0; ee < 4; ++ee) {
        const float lb = isL ? lin_b[r0 + ee] : 0.f;
        float* dst = ws + ((size_t)(b * 512 + r0 + ee) * 128 + k0);
        *(v4f*)dst       = (v4f){acc[ee][0]+lb, acc[ee][1]+lb, acc[ee][2]+lb, acc[ee][3]+lb};
        *(v4f*)(dst + 4) = (v4f){acc[ee][4]+lb, acc[ee][5]+lb, acc[ee][6]+lb, acc[ee][7]+lb};
    }
}

// ---------------- K2: logits + softmax + PV + sigmoid ----------------
// grid (32 b, 8 it of 16 i-rows), 256 thr.
// phase1: lane 2i x 4j, packed f32; R ring depth 6; L dup-pairs in LDS.
// phase2: all-LDS (x transposed into LDS at block start, pad-130 rows).
__global__ __launch_bounds__(256,1) void k_attn(
    const float* __restrict__ x, const float* __restrict__ bias,
    const float* __restrict__ ws, float* __restrict__ out)
{
    __shared__ float Lt2[256 * 32];    // (l,l) dup pairs: Lt2[e*32 + il*2 + {0,1}]  32 KB
    __shared__ float xT[128 * 130];    // xT[j*130 + w] = x[b][w][j]                 66.6 KB
    __shared__ float att[16 * 132];    //                                            8.4 KB

    const int t = threadIdx.x;
    const int b = blockIdx.x, it = blockIdx.y;
    const float* Pb = ws + (size_t)b * 65536;

    // ---- stage L dup-pairs (1024 f4 slots) ----
    {
        const float* Lsrc = Pb + it * 16;
        #pragma unroll
        for (int q = 0; q < 4; ++q) {
            const int idx = t + q * 256;             // 0..1023
            const int e = idx >> 2, il4 = (idx & 3) * 4;
            v4f lv = *(const v4f*)(Lsrc + e * 128 + il4);
            *(v4f*)&Lt2[e * 32 + il4 * 2]     = __builtin_shufflevector(lv, lv, 0,0,1,1);
            *(v4f*)&Lt2[e * 32 + il4 * 2 + 4] = __builtin_shufflevector(lv, lv, 2,2,3,3);
        }
    }
    // ---- stage x transposed (4096 f4 slots) ----
    {
        const float* xb = x + b * 16384;
        #pragma unroll
        for (int q = 0; q < 16; ++q) {
            const int idx = t + q * 256;             // 0..4095
            const int w = idx >> 5, j4 = (idx & 31) * 4;
            v4f xv = *(const v4f*)(xb + w * 128 + j4);
            xT[(j4 + 0) * 130 + w] = xv.x;
            xT[(j4 + 1) * 130 + w] = xv.y;
            xT[(j4 + 2) * 130 + w] = xv.z;
            xT[(j4 + 3) * 130 + w] = xv.w;
        }
    }
    __syncthreads();

    // ---- phase 1: logits, packed f32, R ring depth 6 ----
    const int jp = t & 31, iq = t >> 5;
    const int j0 = jp * 4, il0 = iq * 2;
    const float* Rg  = Pb + 32768 + j0;
    const float* a6d = ws + WS_A6D;
    const float* a4d = ws + WS_A4D;

    v2f accp00 = {0,0}, accp01 = {0,0}, accp10 = {0,0}, accp11 = {0,0};
    v2f drp0 = {0,0}, drp1 = {0,0};
    float dl0 = 0.f, dl1 = 0.f;

    v4f rb[6][4], a6b[2][2], a4b[2][2], lb[2][4];

#define K2_RLD(s, c) do {                                                   \
    _Pragma("unroll") for (int u = 0; u < 4; ++u)                           \
      rb[s][u] = *(const v4f*)(Rg + ((c)*4 + u) * 128); } while(0)

#define K2_ALD(s, c) do {                                                   \
    a6b[s][0] = *(const v4f*)(a6d + (c)*8);                                 \
    a6b[s][1] = *(const v4f*)(a6d + (c)*8 + 4);                             \
    a4b[s][0] = *(const v4f*)(a4d + (c)*8);                                 \
    a4b[s][1] = *(const v4f*)(a4d + (c)*8 + 4);                             \
    _Pragma("unroll") for (int u = 0; u < 4; ++u)                           \
      lb[s][u] = *(const v4f*)&Lt2[((c)*4 + u) * 32 + il0 * 2]; } while(0)

#define K2_CMP(sr, sa) do {                                                 \
    _Pragma("unroll") for (int u = 0; u < 4; ++u) {                         \
      v4f rv = rb[sr][u]; v2f r01 = vlo(rv), r23 = vhi(rv);                 \
      v4f lv = lb[sa][u]; v2f l00 = vlo(lv), l11 = vhi(lv);                 \
      v4f a6q = a6b[sa][u>>1]; v2f a6p = (u&1) ? vhi(a6q) : vlo(a6q);       \
      v4f a4q = a4b[sa][u>>1]; v2f a4p = (u&1) ? vhi(a4q) : vlo(a4q);       \
      dl0 = fmaf(a6p.x, l00.x, dl0);                                        \
      dl1 = fmaf(a6p.x, l11.x, dl1);                                        \
      drp0 = pfma(a6p, r01, drp0);                                          \
      drp1 = pfma(a6p, r23, drp1);                                          \
      v2f s;                                                                \
      s = l00 + r01; accp00 = pfma(a4p, pabs(s), accp00);                   \
      s = l00 + r23; accp01 = pfma(a4p, pabs(s), accp01);                   \
      s = l11 + r01; accp10 = pfma(a4p, pabs(s), accp10);                   \
      s = l11 + r23; accp11 = pfma(a4p, pabs(s), accp11); } } while(0)

    K2_RLD(0,0); K2_RLD(1,1); K2_RLD(2,2); K2_RLD(3,3); K2_RLD(4,4);
    K2_ALD(0,0);
    #pragma unroll
    for (int c = 0; c < 64; ++c) {
        if (c + 5 < 64) K2_RLD((c + 5) % 6, c + 5);
        if (c + 1 < 64) K2_ALD((c + 1) & 1, c + 1);
        K2_CMP(c % 6, c & 1);
    }

    // ---- softmax over j (row lives in one 32-lane half-wave) ----
    const int i0 = it * 16 + il0;
    float ev[2][4];
    ev[0][0] = accp00.x + dl0 + drp0.x;  ev[0][1] = accp00.y + dl0 + drp0.y;
    ev[0][2] = accp01.x + dl0 + drp1.x;  ev[0][3] = accp01.y + dl0 + drp1.y;
    ev[1][0] = accp10.x + dl1 + drp0.x;  ev[1][1] = accp10.y + dl1 + drp0.y;
    ev[1][2] = accp11.x + dl1 + drp1.x;  ev[1][3] = accp11.y + dl1 + drp1.y;

    #pragma unroll
    for (int ii = 0; ii < 2; ++ii) {
        v4f bi = *(const v4f*)(bias + (i0 + ii) * 128 + j0);
        float e0 = ev[ii][0] + bi.x, e1 = ev[ii][1] + bi.y;
        float e2 = ev[ii][2] + bi.z, e3 = ev[ii][3] + bi.w;
        float m = fmaxf(fmaxf(e0, e1), fmaxf(e2, e3));
        #pragma unroll
        for (int d = 1; d <= 16; d <<= 1) m = fmaxf(m, __shfl_xor(m, d));
        float p0 = __expf(e0 - m), p1 = __expf(e1 - m);
        float p2 = __expf(e2 - m), p3 = __expf(e3 - m);
        float s = p0 + p1 + p2 + p3;
        #pragma unroll
        for (int d = 1; d <= 16; d <<= 1) s += __shfl_xor(s, d);
        const float inv = 1.f / s;
        *(v4f*)&att[(il0 + ii) * 132 + j0] = (v4f){p0*inv, p1*inv, p2*inv, p3*inv};
    }
    __syncthreads();

    // ---- phase 2: all-LDS PV + sigmoid; lane: 2 w x 4 i ----
    const int iq2 = t & 3, wp = t >> 2;
    const int i4 = iq2 * 4, w0 = wp * 2;
    float o[2][4] = {};
    #pragma unroll
    for (int jc = 0; jc < 32; ++jc) {
        v4f av[4]; v2f xv[4];
        #pragma unroll
        for (int q = 0; q < 4; ++q)
            av[q] = *(const v4f*)&att[(i4 + q) * 132 + jc * 4];
        #pragma unroll
        for (int u = 0; u < 4; ++u)
            xv[u] = *(const v2f*)&xT[(jc * 4 + u) * 130 + w0];
        #pragma unroll
        for (int u = 0; u < 4; ++u)
            #pragma unroll
            for (int q = 0; q < 4; ++q) {
                o[0][q] = fmaf(xv[u].x, av[q][u], o[0][q]);
                o[1][q] = fmaf(xv[u].y, av[q][u], o[1][q]);
            }
    }
    #pragma unroll
    for (int w = 0; w < 2; ++w) {
        v4f r;
        r.x = 1.f / (1.f + __expf(-o[w][0]));
        r.y = 1.f / (1.f + __expf(-o[w][1]));
        r.z = 1.f / (1.f + __expf(-o[w][2]));
        r.w = 1.f / (1.f + __expf(-o[w][3]));
        *(v4f*)(out + (size_t)b * 16384 + (w0 + w) * 128 + it * 16 + i4) = r;
    }
}

extern "C" void kernel_launch(void* const* d_in, const int* in_sizes, int n_in,
                              void* d_out, int out_size, void* d_ws, size_t ws_size,
                              hipStream_t stream) {
    const float* x     = (const float*)d_in[0];
    const float* lin_w = (const float*)d_in[1];
    const float* lin_b = (const float*)d_in[2];
    const float* a     = (const float*)d_in[3];
    const float* bias  = (const float*)d_in[4];
    float* ws  = (float*)d_ws;
    float* out = (float*)d_out;

    k_linear<<<dim3(32, 8), 256, 0, stream>>>(x, lin_w, lin_b, a, ws);
    k_attn  <<<dim3(32, 8), 256, 0, stream>>>(x, bias, ws, out);
}

// Round 5
// 297.432 us; speedup vs baseline: 4.7793x; 4.7793x over previous
//
#include <hip/hip_runtime.h>

// FeatureAttentionLayer: B=32, W=128, K=128, E=256, fp32.
//   L[i][e] = sum_w x[b][w][i]*lin_w[e][w] + lin_b[e]
//   R[j][e] = sum_w x[b][w][j]*lin_w[e][128+w]
//   e[i][j] = 0.6(dL[i]+dR[j]) + sum_e 0.4a[e]|L+R| + bias   (LReLU identity)
//   att = softmax_j; out[b][w][i] = sigmoid(sum_j att[i][j]*x[b][w][j])
//
// ws: P[b][r][k] (r<256: L^T rows; r>=256: R^T rows), 2M floats; a6/a4 @ 2M.
// Round-5: round-4's deep VGPR rings spilled (1.3GB scratch traffic). Latency
// now hidden in LDS instead: K2 stages R in 32KB chunks (reg-staged dbuf,
// only 8 v4f in flight), e-loop is all-LDS; phase-2 x staged into dead R
// buffers with XOR swizzle. K1: 2 blocks/CU + VGPR cap 128.

typedef float v2f __attribute__((ext_vector_type(2)));
typedef float v4f __attribute__((ext_vector_type(4)));

#define WS_A6  2097152
#define WS_A4  (2097152 + 256)

// ---------------- K1: projection GEMM ----------------
// grid (32 b, 2 kt, 8 rt), 256 thr; thread 4k x 4r; ping-pong depth 2.
__global__ __launch_bounds__(256, 2) void k_linear(
    const float* __restrict__ x, const float* __restrict__ lin_w,
    const float* __restrict__ lin_b, const float* __restrict__ a,
    float* __restrict__ ws)
{
    const int t = threadIdx.x;
    const int b = blockIdx.x, kt = blockIdx.y, rt = blockIdx.z;

    if (b == 0 && kt == 0 && rt == 0) {   // fold a once (K2 is stream-ordered after)
        float av = a[t];
        ws[WS_A6 + t] = 0.6f * av;
        ws[WS_A4 + t] = 0.4f * av;
    }

    const int kp = t & 15, ep = t >> 4;
    const int k0 = kt * 64 + kp * 4;
    const int r0 = rt * 64 + ep * 4;
    const bool isL = (rt < 4);

    const float* xb = x + b * 16384 + k0;
    const float* Ab = isL ? (lin_w + (size_t)r0 * 256)
                          : (lin_w + (size_t)(r0 - 256) * 256 + 128);

    float acc[4][4] = {};   // [ee][kk]
    v4f xA[4], wA[4], xB[4], wB[4];

#define K1LD(X, W, c) do {                                            \
    _Pragma("unroll") for (int ww = 0; ww < 4; ++ww)                  \
      X[ww] = *(const v4f*)(xb + ((c) * 4 + ww) * 128);               \
    _Pragma("unroll") for (int ee = 0; ee < 4; ++ee)                  \
      W[ee] = *(const v4f*)(Ab + ee * 256 + (c) * 4); } while (0)

#define K1CP(X, W) do {                                               \
    _Pragma("unroll") for (int ww = 0; ww < 4; ++ww)                  \
      _Pragma("unroll") for (int ee = 0; ee < 4; ++ee) {              \
        const float wv = W[ee][ww];                                   \
        _Pragma("unroll") for (int kk = 0; kk < 4; ++kk)              \
          acc[ee][kk] = fmaf(X[ww][kk], wv, acc[ee][kk]); } } while (0)

    K1LD(xA, wA, 0);
    #pragma unroll
    for (int c = 0; c < 32; c += 2) {
        K1LD(xB, wB, c + 1);
        K1CP(xA, wA);
        if (c + 2 < 32) K1LD(xA, wA, c + 2);
        K1CP(xB, wB);
    }

    #pragma unroll
    for (int ee = 0; ee < 4; ++ee) {
        const float lb = isL ? lin_b[r0 + ee] : 0.f;
        float* dst = ws + ((size_t)(b * 512 + r0 + ee) * 128 + k0);
        *(v4f*)dst = (v4f){acc[ee][0] + lb, acc[ee][1] + lb,
                           acc[ee][2] + lb, acc[ee][3] + lb};
    }
}

// ---------------- K2: logits + softmax + PV + sigmoid ----------------
// grid (32 b, 8 it of 16 i-rows), 256 thr.
// R staged in LDS (4 chunks of 64 e-rows, double-buffered via 8 v4f regs);
// e-loop all-LDS. Phase-2 x transposed into the dead R buffers (XOR swizzle).
__global__ __launch_bounds__(256, 1) void k_attn(
    const float* __restrict__ x, const float* __restrict__ bias,
    const float* __restrict__ ws, float* __restrict__ out)
{
    __shared__ float Rs[2][8192];      // 64 KB; reused as xT after e-loop
    __shared__ float Lt[256 * 16];     // 16 KB: Lt[e*16+il]
    __shared__ float att[16 * 132];    // 8.4 KB
    __shared__ float as6[256], as4[256];

    const int t = threadIdx.x;
    const int b = blockIdx.x, it = blockIdx.y;
    const float* Pb = ws + (size_t)b * 65536;
    const float* Rsrc = Pb + 32768;    // R^T rows, contiguous 32 KB per chunk

    v4f rx[8];
#define RLOAD(n_) do { const float* s_ = Rsrc + (n_) * 8192 + t * 4;  \
    _Pragma("unroll") for (int q = 0; q < 8; ++q)                     \
      rx[q] = *(const v4f*)(s_ + q * 1024); } while (0)

    RLOAD(0);

    // stage L^T tile (coalesced) + a-vectors
    {
        const float* Ls = Pb + it * 16;
        #pragma unroll
        for (int q = 0; q < 4; ++q) {
            const int idx = t + q * 256;
            const int e = idx >> 2, il4 = (idx & 3) * 4;
            *(v4f*)&Lt[e * 16 + il4] = *(const v4f*)(Ls + e * 128 + il4);
        }
    }
    as6[t] = ws[WS_A6 + t];
    as4[t] = ws[WS_A4 + t];

    const int jp = t & 31, iq = t >> 5;
    const int j0 = jp * 4, il0 = iq * 2;

    float acc0[4] = {}, acc1[4] = {};      // sum 0.4a*|L+R| per jj, rows il0/il0+1
    float dr[4] = {};                      // sum 0.6a*R per jj
    float dl0 = 0.f, dl1 = 0.f;            // sum 0.6a*L per row

    #pragma unroll 1
    for (int n = 0; n < 4; ++n) {
        float* rs = &Rs[n & 1][0];
        {   // commit staged chunk n to LDS (linear, conflict-free sweep)
            float* d_ = rs + t * 4;
            #pragma unroll
            for (int q = 0; q < 8; ++q) *(v4f*)(d_ + q * 1024) = rx[q];
        }
        if (n < 3) RLOAD(n + 1);           // global latency covered by compute below
        __syncthreads();

        const int eg0 = n * 64;
        #pragma unroll
        for (int g = 0; g < 16; ++g) {
            const int e0 = g * 4, eg = eg0 + e0;
            v4f rv[4]; float2 lv[4];
            #pragma unroll
            for (int u = 0; u < 4; ++u) {
                rv[u] = *(const v4f*)&rs[(e0 + u) * 128 + j0];
                lv[u] = *(const float2*)&Lt[(eg + u) * 16 + il0];
            }
            const v4f a6v = *(const v4f*)&as6[eg];
            const v4f a4v = *(const v4f*)&as4[eg];
            #pragma unroll
            for (int u = 0; u < 4; ++u) {
                const float a6u = a6v[u], a4u = a4v[u];
                const float l0 = lv[u].x, l1 = lv[u].y;
                dl0 = fmaf(a6u, l0, dl0);
                dl1 = fmaf(a6u, l1, dl1);
                #pragma unroll
                for (int jj = 0; jj < 4; ++jj) {
                    const float r = rv[u][jj];
                    dr[jj]   = fmaf(a6u, r, dr[jj]);
                    acc0[jj] = fmaf(a4u, fabsf(l0 + r), acc0[jj]);
                    acc1[jj] = fmaf(a4u, fabsf(l1 + r), acc1[jj]);
                }
            }
        }
    }
    __syncthreads();                       // all waves done with Rs -> reuse as xT

    // stage xT[j][w ^ swz(j)] into the dead R buffers (64 KB exactly).
    // swz = ((j>>2)&15)<<1 : write ~2-way (free), read conflict-free, keeps
    // 8B alignment for the v2f reads.
    float* xT = &Rs[0][0];
    {
        const float* xg = x + b * 16384;
        #pragma unroll
        for (int q = 0; q < 16; ++q) {
            const int idx = t + q * 256;
            const int w = idx >> 5, j4 = (idx & 31) * 4;
            const int s = ((j4 >> 2) & 15) << 1;
            const v4f xv = *(const v4f*)(xg + w * 128 + j4);
            xT[(j4 + 0) * 128 + (w ^ s)] = xv[0];
            xT[(j4 + 1) * 128 + (w ^ s)] = xv[1];
            xT[(j4 + 2) * 128 + (w ^ s)] = xv[2];
            xT[(j4 + 3) * 128 + (w ^ s)] = xv[3];
        }
    }

    // softmax over j (row lives in one 32-lane half-wave)
    const int i0r = it * 16 + il0;
    float ev0[4], ev1[4];
    {
        const v4f b0 = *(const v4f*)(bias + (i0r + 0) * 128 + j0);
        const v4f b1 = *(const v4f*)(bias + (i0r + 1) * 128 + j0);
        #pragma unroll
        for (int jj = 0; jj < 4; ++jj) {
            ev0[jj] = acc0[jj] + dl0 + dr[jj] + b0[jj];
            ev1[jj] = acc1[jj] + dl1 + dr[jj] + b1[jj];
        }
    }
#define SOFTMAX_ROW(EV, ROW) do {                                               \
    float m_ = fmaxf(fmaxf(EV[0], EV[1]), fmaxf(EV[2], EV[3]));                 \
    _Pragma("unroll") for (int d_ = 1; d_ <= 16; d_ <<= 1)                      \
        m_ = fmaxf(m_, __shfl_xor(m_, d_));                                     \
    float p0 = __expf(EV[0] - m_), p1 = __expf(EV[1] - m_);                     \
    float p2 = __expf(EV[2] - m_), p3 = __expf(EV[3] - m_);                     \
    float s_ = p0 + p1 + p2 + p3;                                               \
    _Pragma("unroll") for (int d_ = 1; d_ <= 16; d_ <<= 1)                      \
        s_ += __shfl_xor(s_, d_);                                               \
    const float inv_ = 1.f / s_;                                                \
    *(v4f*)&att[(ROW) * 132 + j0] =                                             \
        (v4f){p0 * inv_, p1 * inv_, p2 * inv_, p3 * inv_}; } while (0)

    SOFTMAX_ROW(ev0, il0 + 0);
    SOFTMAX_ROW(ev1, il0 + 1);
    __syncthreads();

    // phase 2: out[b][w][i] = sigmoid(sum_j att[i][j]*x[b][w][j]); lane 2w x 4i
    const int iq2 = t & 3, wp = t >> 2;
    const int i4 = iq2 * 4, w0 = wp * 2;
    float o[2][4] = {};
    #pragma unroll 4
    for (int jc = 0; jc < 32; ++jc) {
        const int wx = w0 ^ ((jc & 15) << 1);
        v4f av[4]; v2f xv[4];
        #pragma unroll
        for (int q = 0; q < 4; ++q)
            av[q] = *(const v4f*)&att[(i4 + q) * 132 + jc * 4];
        #pragma unroll
        for (int u = 0; u < 4; ++u)
            xv[u] = *(const v2f*)&xT[(jc * 4 + u) * 128 + wx];
        #pragma unroll
        for (int u = 0; u < 4; ++u)
            #pragma unroll
            for (int q = 0; q < 4; ++q) {
                o[0][q] = fmaf(xv[u].x, av[q][u], o[0][q]);
                o[1][q] = fmaf(xv[u].y, av[q][u], o[1][q]);
            }
    }
    #pragma unroll
    for (int w = 0; w < 2; ++w) {
        v4f r;
        r[0] = 1.f / (1.f + __expf(-o[w][0]));
        r[1] = 1.f / (1.f + __expf(-o[w][1]));
        r[2] = 1.f / (1.f + __expf(-o[w][2]));
        r[3] = 1.f / (1.f + __expf(-o[w][3]));
        *(v4f*)(out + (size_t)b * 16384 + (w0 + w) * 128 + it * 16 + i4) = r;
    }
}

extern "C" void kernel_launch(void* const* d_in, const int* in_sizes, int n_in,
                              void* d_out, int out_size, void* d_ws, size_t ws_size,
                              hipStream_t stream) {
    const float* x     = (const float*)d_in[0];
    const float* lin_w = (const float*)d_in[1];
    const float* lin_b = (const float*)d_in[2];
    const float* a     = (const float*)d_in[3];
    const float* bias  = (const float*)d_in[4];
    float* ws  = (float*)d_ws;
    float* out = (float*)d_out;

    k_linear<<<dim3(32, 2, 8), 256, 0, stream>>>(x, lin_w, lin_b, a, ws);
    k_attn  <<<dim3(32, 8), 256, 0, stream>>>(x, bias, ws, out);
}

// Round 6
// 36.436 us; speedup vs baseline: 39.0138x; 8.1630x over previous
//
#include <hip/hip_runtime.h>

// FeatureAttentionLayer: B=32, W=128, K=128, E=256, fp32.
//   L[i][e] = sum_w x[b][w][i]*lin_w[e][w] + lin_b[e]
//   R[j][e] = sum_w x[b][w][j]*lin_w[e][128+w]
//   e[i][j] = 0.6(dL[i]+dR[j]) + sum_e 0.4a[e]|L+R| + bias   (LReLU identity)
//   att = softmax_j; out[b][w][i] = sigmoid(sum_j att[i][j]*x[b][w][j])
//
// ws: P[b][r][k] (r<256: L^T rows; r>=256: R^T rows), 2M floats; a6/a4 @ 2M.
// Round-6: K1 rebuilt on the K2 recipe — stage x-half + A-tile in LDS once,
// all-LDS compute loop, no register rings, no VGPR cap (round-5's 128-cap +
// full unroll spilled: 390MB FETCH of scratch). K2 unchanged (at ~6us, near
// its 4.7us VALU floor).

typedef float v2f __attribute__((ext_vector_type(2)));
typedef float v4f __attribute__((ext_vector_type(4)));

#define WS_A6  2097152
#define WS_A4  (2097152 + 256)

// ---------------- K1: projection GEMM, LDS-staged ----------------
// grid (32 b, 2 kt, 8 rt), 256 thr; 2 blocks/CU (64 KB LDS each).
// thread: 4 r (ep) x 4 k (kp); compute loop reads LDS only.
__global__ __launch_bounds__(256) void k_linear(
    const float* __restrict__ x, const float* __restrict__ lin_w,
    const float* __restrict__ lin_b, const float* __restrict__ a,
    float* __restrict__ ws)
{
    __shared__ float xs[128 * 64];   // xs[w][kk], kk = k - kt*64   (32 KB)
    __shared__ float As[64 * 128];   // As[rr][w], rr = r - rt*64   (32 KB)

    const int t = threadIdx.x;
    const int b = blockIdx.x, kt = blockIdx.y, rt = blockIdx.z;

    if (b == 0 && kt == 0 && rt == 0) {   // fold a once (K2 is stream-ordered after)
        float av = a[t];
        ws[WS_A6 + t] = 0.6f * av;
        ws[WS_A4 + t] = 0.4f * av;
    }

    const bool isL = (rt < 4);

    // stage x[b][:, kt*64 .. +63]  (2048 v4f slots)
    {
        const float* xg = x + b * 16384 + kt * 64;
        #pragma unroll
        for (int q = 0; q < 8; ++q) {
            const int idx = t + q * 256;
            const int w = idx >> 4, k4 = (idx & 15) * 4;
            *(v4f*)&xs[w * 64 + k4] = *(const v4f*)(xg + w * 128 + k4);
        }
    }
    // stage A-tile: rows r0..r0+63 of A[r][w] (=lin_w[r][0:128] or lin_w[r-256][128:256])
    {
        const float* Ag = isL ? (lin_w + (size_t)(rt * 64) * 256)
                              : (lin_w + (size_t)(rt * 64 - 256) * 256 + 128);
        #pragma unroll
        for (int q = 0; q < 8; ++q) {
            const int idx = t + q * 256;
            const int rr = idx >> 5, w4 = (idx & 31) * 4;
            *(v4f*)&As[rr * 128 + w4] = *(const v4f*)(Ag + rr * 256 + w4);
        }
    }
    __syncthreads();

    const int kp = t & 15, ep = t >> 4;
    const int k4 = kp * 4;
    const int rr0 = ep * 4;

    float acc[4][4] = {};   // [ee][kk]

    #pragma unroll 4
    for (int c = 0; c < 32; ++c) {
        v4f xv[4], wv[4];
        #pragma unroll
        for (int ww = 0; ww < 4; ++ww)
            xv[ww] = *(const v4f*)&xs[(c * 4 + ww) * 64 + k4];
        #pragma unroll
        for (int ee = 0; ee < 4; ++ee)
            wv[ee] = *(const v4f*)&As[(rr0 + ee) * 128 + c * 4];
        #pragma unroll
        for (int ww = 0; ww < 4; ++ww)
            #pragma unroll
            for (int ee = 0; ee < 4; ++ee) {
                const float w_ = wv[ee][ww];
                #pragma unroll
                for (int kk = 0; kk < 4; ++kk)
                    acc[ee][kk] = fmaf(xv[ww][kk], w_, acc[ee][kk]);
            }
    }

    const int r0 = rt * 64 + rr0;
    const int k0 = kt * 64 + k4;
    #pragma unroll
    for (int ee = 0; ee < 4; ++ee) {
        const float lb = isL ? lin_b[r0 + ee] : 0.f;
        float* dst = ws + ((size_t)(b * 512 + r0 + ee) * 128 + k0);
        *(v4f*)dst = (v4f){acc[ee][0] + lb, acc[ee][1] + lb,
                           acc[ee][2] + lb, acc[ee][3] + lb};
    }
}

// ---------------- K2: logits + softmax + PV + sigmoid (unchanged) ----------------
// grid (32 b, 8 it of 16 i-rows), 256 thr.
// R staged in LDS (4 chunks of 64 e-rows, double-buffered via 8 v4f regs);
// e-loop all-LDS. Phase-2 x transposed into the dead R buffers (XOR swizzle).
__global__ __launch_bounds__(256, 1) void k_attn(
    const float* __restrict__ x, const float* __restrict__ bias,
    const float* __restrict__ ws, float* __restrict__ out)
{
    __shared__ float Rs[2][8192];      // 64 KB; reused as xT after e-loop
    __shared__ float Lt[256 * 16];     // 16 KB: Lt[e*16+il]
    __shared__ float att[16 * 132];    // 8.4 KB
    __shared__ float as6[256], as4[256];

    const int t = threadIdx.x;
    const int b = blockIdx.x, it = blockIdx.y;
    const float* Pb = ws + (size_t)b * 65536;
    const float* Rsrc = Pb + 32768;    // R^T rows, contiguous 32 KB per chunk

    v4f rx[8];
#define RLOAD(n_) do { const float* s_ = Rsrc + (n_) * 8192 + t * 4;  \
    _Pragma("unroll") for (int q = 0; q < 8; ++q)                     \
      rx[q] = *(const v4f*)(s_ + q * 1024); } while (0)

    RLOAD(0);

    // stage L^T tile (coalesced) + a-vectors
    {
        const float* Ls = Pb + it * 16;
        #pragma unroll
        for (int q = 0; q < 4; ++q) {
            const int idx = t + q * 256;
            const int e = idx >> 2, il4 = (idx & 3) * 4;
            *(v4f*)&Lt[e * 16 + il4] = *(const v4f*)(Ls + e * 128 + il4);
        }
    }
    as6[t] = ws[WS_A6 + t];
    as4[t] = ws[WS_A4 + t];

    const int jp = t & 31, iq = t >> 5;
    const int j0 = jp * 4, il0 = iq * 2;

    float acc0[4] = {}, acc1[4] = {};      // sum 0.4a*|L+R| per jj, rows il0/il0+1
    float dr[4] = {};                      // sum 0.6a*R per jj
    float dl0 = 0.f, dl1 = 0.f;            // sum 0.6a*L per row

    #pragma unroll 1
    for (int n = 0; n < 4; ++n) {
        float* rs = &Rs[n & 1][0];
        {   // commit staged chunk n to LDS (linear, conflict-free sweep)
            float* d_ = rs + t * 4;
            #pragma unroll
            for (int q = 0; q < 8; ++q) *(v4f*)(d_ + q * 1024) = rx[q];
        }
        if (n < 3) RLOAD(n + 1);           // global latency covered by compute below
        __syncthreads();

        const int eg0 = n * 64;
        #pragma unroll
        for (int g = 0; g < 16; ++g) {
            const int e0 = g * 4, eg = eg0 + e0;
            v4f rv[4]; float2 lv[4];
            #pragma unroll
            for (int u = 0; u < 4; ++u) {
                rv[u] = *(const v4f*)&rs[(e0 + u) * 128 + j0];
                lv[u] = *(const float2*)&Lt[(eg + u) * 16 + il0];
            }
            const v4f a6v = *(const v4f*)&as6[eg];
            const v4f a4v = *(const v4f*)&as4[eg];
            #pragma unroll
            for (int u = 0; u < 4; ++u) {
                const float a6u = a6v[u], a4u = a4v[u];
                const float l0 = lv[u].x, l1 = lv[u].y;
                dl0 = fmaf(a6u, l0, dl0);
                dl1 = fmaf(a6u, l1, dl1);
                #pragma unroll
                for (int jj = 0; jj < 4; ++jj) {
                    const float r = rv[u][jj];
                    dr[jj]   = fmaf(a6u, r, dr[jj]);
                    acc0[jj] = fmaf(a4u, fabsf(l0 + r), acc0[jj]);
                    acc1[jj] = fmaf(a4u, fabsf(l1 + r), acc1[jj]);
                }
            }
        }
    }
    __syncthreads();                       // all waves done with Rs -> reuse as xT

    // stage xT[j][w ^ swz(j)] into the dead R buffers (64 KB exactly).
    // swz = ((j>>2)&15)<<1 : write ~2-way (free), read conflict-free, keeps
    // 8B alignment for the v2f reads.
    float* xT = &Rs[0][0];
    {
        const float* xg = x + b * 16384;
        #pragma unroll
        for (int q = 0; q < 16; ++q) {
            const int idx = t + q * 256;
            const int w = idx >> 5, j4 = (idx & 31) * 4;
            const int s = ((j4 >> 2) & 15) << 1;
            const v4f xv = *(const v4f*)(xg + w * 128 + j4);
            xT[(j4 + 0) * 128 + (w ^ s)] = xv[0];
            xT[(j4 + 1) * 128 + (w ^ s)] = xv[1];
            xT[(j4 + 2) * 128 + (w ^ s)] = xv[2];
            xT[(j4 + 3) * 128 + (w ^ s)] = xv[3];
        }
    }

    // softmax over j (row lives in one 32-lane half-wave)
    const int i0r = it * 16 + il0;
    float ev0[4], ev1[4];
    {
        const v4f b0 = *(const v4f*)(bias + (i0r + 0) * 128 + j0);
        const v4f b1 = *(const v4f*)(bias + (i0r + 1) * 128 + j0);
        #pragma unroll
        for (int jj = 0; jj < 4; ++jj) {
            ev0[jj] = acc0[jj] + dl0 + dr[jj] + b0[jj];
            ev1[jj] = acc1[jj] + dl1 + dr[jj] + b1[jj];
        }
    }
#define SOFTMAX_ROW(EV, ROW) do {                                               \
    float m_ = fmaxf(fmaxf(EV[0], EV[1]), fmaxf(EV[2], EV[3]));                 \
    _Pragma("unroll") for (int d_ = 1; d_ <= 16; d_ <<= 1)                      \
        m_ = fmaxf(m_, __shfl_xor(m_, d_));                                     \
    float p0 = __expf(EV[0] - m_), p1 = __expf(EV[1] - m_);                     \
    float p2 = __expf(EV[2] - m_), p3 = __expf(EV[3] - m_);                     \
    float s_ = p0 + p1 + p2 + p3;                                               \
    _Pragma("unroll") for (int d_ = 1; d_ <= 16; d_ <<= 1)                      \
        s_ += __shfl_xor(s_, d_);                                               \
    const float inv_ = 1.f / s_;                                                \
    *(v4f*)&att[(ROW) * 132 + j0] =                                             \
        (v4f){p0 * inv_, p1 * inv_, p2 * inv_, p3 * inv_}; } while (0)

    SOFTMAX_ROW(ev0, il0 + 0);
    SOFTMAX_ROW(ev1, il0 + 1);
    __syncthreads();

    // phase 2: out[b][w][i] = sigmoid(sum_j att[i][j]*x[b][w][j]); lane 2w x 4i
    const int iq2 = t & 3, wp = t >> 2;
    const int i4 = iq2 * 4, w0 = wp * 2;
    float o[2][4] = {};
    #pragma unroll 4
    for (int jc = 0; jc < 32; ++jc) {
        const int wx = w0 ^ ((jc & 15) << 1);
        v4f av[4]; v2f xv[4];
        #pragma unroll
        for (int q = 0; q < 4; ++q)
            av[q] = *(const v4f*)&att[(i4 + q) * 132 + jc * 4];
        #pragma unroll
        for (int u = 0; u < 4; ++u)
            xv[u] = *(const v2f*)&xT[(jc * 4 + u) * 128 + wx];
        #pragma unroll
        for (int u = 0; u < 4; ++u)
            #pragma unroll
            for (int q = 0; q < 4; ++q) {
                o[0][q] = fmaf(xv[u].x, av[q][u], o[0][q]);
                o[1][q] = fmaf(xv[u].y, av[q][u], o[1][q]);
            }
    }
    #pragma unroll
    for (int w = 0; w < 2; ++w) {
        v4f r;
        r[0] = 1.f / (1.f + __expf(-o[w][0]));
        r[1] = 1.f / (1.f + __expf(-o[w][1]));
        r[2] = 1.f / (1.f + __expf(-o[w][2]));
        r[3] = 1.f / (1.f + __expf(-o[w][3]));
        *(v4f*)(out + (size_t)b * 16384 + (w0 + w) * 128 + it * 16 + i4) = r;
    }
}

extern "C" void kernel_launch(void* const* d_in, const int* in_sizes, int n_in,
                              void* d_out, int out_size, void* d_ws, size_t ws_size,
                              hipStream_t stream) {
    const float* x     = (const float*)d_in[0];
    const float* lin_w = (const float*)d_in[1];
    const float* lin_b = (const float*)d_in[2];
    const float* a     = (const float*)d_in[3];
    const float* bias  = (const float*)d_in[4];
    float* ws  = (float*)d_ws;
    float* out = (float*)d_out;

    k_linear<<<dim3(32, 2, 8), 256, 0, stream>>>(x, lin_w, lin_b, a, ws);
    k_attn  <<<dim3(32, 8), 256, 0, stream>>>(x, bias, ws, out);
}

// Round 7
// 35.800 us; speedup vs baseline: 39.7079x; 1.0178x over previous
//
#include <hip/hip_runtime.h>

// FeatureAttentionLayer: B=32, W=128, K=128, E=256, fp32.
//   L[i][e] = sum_w x[b][w][i]*lin_w[e][w] + lin_b[e]
//   R[j][e] = sum_w x[b][w][j]*lin_w[e][128+w]
//   e[i][j] = 0.6(dL[i]+dR[j]) + sum_e 0.4a[e]|L+R| + bias   (LReLU identity)
//   att = softmax_j; out[b][w][i] = sigmoid(sum_j att[i][j]*x[b][w][j])
//
// ws: P[b][r][k] (r<256: L^T rows; r>=256: R^T rows), 2M floats; a6/a4 @ 2M.
// Round-7: K1's As tile had row stride 512B == 0 mod 128B, so the 4 ep-groups
// of each wave hit the same bank set on every weight read -> 4-way b128 bank
// conflict on the hot loop. Pad stride to 132 floats (528B, 16B-aligned;
// ep offsets 0/64/0/64 mod 128B = 2-way = free). Only change this round.

typedef float v2f __attribute__((ext_vector_type(2)));
typedef float v4f __attribute__((ext_vector_type(4)));

#define WS_A6  2097152
#define WS_A4  (2097152 + 256)

// ---------------- K1: projection GEMM, LDS-staged ----------------
// grid (32 b, 2 kt, 8 rt), 256 thr; 2 blocks/CU (65.8 KB LDS each).
// thread: 4 r (ep) x 4 k (kp); compute loop reads LDS only.
__global__ __launch_bounds__(256) void k_linear(
    const float* __restrict__ x, const float* __restrict__ lin_w,
    const float* __restrict__ lin_b, const float* __restrict__ a,
    float* __restrict__ ws)
{
    __shared__ float xs[128 * 64];   // xs[w][kk], kk = k - kt*64   (32 KB)
    __shared__ float As[64 * 132];   // As[rr][w], PADDED stride 132 (33 KB)

    const int t = threadIdx.x;
    const int b = blockIdx.x, kt = blockIdx.y, rt = blockIdx.z;

    if (b == 0 && kt == 0 && rt == 0) {   // fold a once (K2 is stream-ordered after)
        float av = a[t];
        ws[WS_A6 + t] = 0.6f * av;
        ws[WS_A4 + t] = 0.4f * av;
    }

    const bool isL = (rt < 4);

    // stage x[b][:, kt*64 .. +63]  (2048 v4f slots)
    {
        const float* xg = x + b * 16384 + kt * 64;
        #pragma unroll
        for (int q = 0; q < 8; ++q) {
            const int idx = t + q * 256;
            const int w = idx >> 4, k4 = (idx & 15) * 4;
            *(v4f*)&xs[w * 64 + k4] = *(const v4f*)(xg + w * 128 + k4);
        }
    }
    // stage A-tile: rows r0..r0+63 of A[r][w] (=lin_w[r][0:128] or lin_w[r-256][128:256])
    {
        const float* Ag = isL ? (lin_w + (size_t)(rt * 64) * 256)
                              : (lin_w + (size_t)(rt * 64 - 256) * 256 + 128);
        #pragma unroll
        for (int q = 0; q < 8; ++q) {
            const int idx = t + q * 256;
            const int rr = idx >> 5, w4 = (idx & 31) * 4;
            *(v4f*)&As[rr * 132 + w4] = *(const v4f*)(Ag + rr * 256 + w4);
        }
    }
    __syncthreads();

    const int kp = t & 15, ep = t >> 4;
    const int k4 = kp * 4;
    const int rr0 = ep * 4;

    float acc[4][4] = {};   // [ee][kk]

    #pragma unroll 4
    for (int c = 0; c < 32; ++c) {
        v4f xv[4], wv[4];
        #pragma unroll
        for (int ww = 0; ww < 4; ++ww)
            xv[ww] = *(const v4f*)&xs[(c * 4 + ww) * 64 + k4];
        #pragma unroll
        for (int ee = 0; ee < 4; ++ee)
            wv[ee] = *(const v4f*)&As[(rr0 + ee) * 132 + c * 4];
        #pragma unroll
        for (int ww = 0; ww < 4; ++ww)
            #pragma unroll
            for (int ee = 0; ee < 4; ++ee) {
                const float w_ = wv[ee][ww];
                #pragma unroll
                for (int kk = 0; kk < 4; ++kk)
                    acc[ee][kk] = fmaf(xv[ww][kk], w_, acc[ee][kk]);
            }
    }

    const int r0 = rt * 64 + rr0;
    const int k0 = kt * 64 + k4;
    #pragma unroll
    for (int ee = 0; ee < 4; ++ee) {
        const float lb = isL ? lin_b[r0 + ee] : 0.f;
        float* dst = ws + ((size_t)(b * 512 + r0 + ee) * 128 + k0);
        *(v4f*)dst = (v4f){acc[ee][0] + lb, acc[ee][1] + lb,
                           acc[ee][2] + lb, acc[ee][3] + lb};
    }
}

// ---------------- K2: logits + softmax + PV + sigmoid (unchanged) ----------------
// grid (32 b, 8 it of 16 i-rows), 256 thr.
// R staged in LDS (4 chunks of 64 e-rows, double-buffered via 8 v4f regs);
// e-loop all-LDS. Phase-2 x transposed into the dead R buffers (XOR swizzle).
__global__ __launch_bounds__(256, 1) void k_attn(
    const float* __restrict__ x, const float* __restrict__ bias,
    const float* __restrict__ ws, float* __restrict__ out)
{
    __shared__ float Rs[2][8192];      // 64 KB; reused as xT after e-loop
    __shared__ float Lt[256 * 16];     // 16 KB: Lt[e*16+il]
    __shared__ float att[16 * 132];    // 8.4 KB
    __shared__ float as6[256], as4[256];

    const int t = threadIdx.x;
    const int b = blockIdx.x, it = blockIdx.y;
    const float* Pb = ws + (size_t)b * 65536;
    const float* Rsrc = Pb + 32768;    // R^T rows, contiguous 32 KB per chunk

    v4f rx[8];
#define RLOAD(n_) do { const float* s_ = Rsrc + (n_) * 8192 + t * 4;  \
    _Pragma("unroll") for (int q = 0; q < 8; ++q)                     \
      rx[q] = *(const v4f*)(s_ + q * 1024); } while (0)

    RLOAD(0);

    // stage L^T tile (coalesced) + a-vectors
    {
        const float* Ls = Pb + it * 16;
        #pragma unroll
        for (int q = 0; q < 4; ++q) {
            const int idx = t + q * 256;
            const int e = idx >> 2, il4 = (idx & 3) * 4;
            *(v4f*)&Lt[e * 16 + il4] = *(const v4f*)(Ls + e * 128 + il4);
        }
    }
    as6[t] = ws[WS_A6 + t];
    as4[t] = ws[WS_A4 + t];

    const int jp = t & 31, iq = t >> 5;
    const int j0 = jp * 4, il0 = iq * 2;

    float acc0[4] = {}, acc1[4] = {};      // sum 0.4a*|L+R| per jj, rows il0/il0+1
    float dr[4] = {};                      // sum 0.6a*R per jj
    float dl0 = 0.f, dl1 = 0.f;            // sum 0.6a*L per row

    #pragma unroll 1
    for (int n = 0; n < 4; ++n) {
        float* rs = &Rs[n & 1][0];
        {   // commit staged chunk n to LDS (linear, conflict-free sweep)
            float* d_ = rs + t * 4;
            #pragma unroll
            for (int q = 0; q < 8; ++q) *(v4f*)(d_ + q * 1024) = rx[q];
        }
        if (n < 3) RLOAD(n + 1);           // global latency covered by compute below
        __syncthreads();

        const int eg0 = n * 64;
        #pragma unroll
        for (int g = 0; g < 16; ++g) {
            const int e0 = g * 4, eg = eg0 + e0;
            v4f rv[4]; float2 lv[4];
            #pragma unroll
            for (int u = 0; u < 4; ++u) {
                rv[u] = *(const v4f*)&rs[(e0 + u) * 128 + j0];
                lv[u] = *(const float2*)&Lt[(eg + u) * 16 + il0];
            }
            const v4f a6v = *(const v4f*)&as6[eg];
            const v4f a4v = *(const v4f*)&as4[eg];
            #pragma unroll
            for (int u = 0; u < 4; ++u) {
                const float a6u = a6v[u], a4u = a4v[u];
                const float l0 = lv[u].x, l1 = lv[u].y;
                dl0 = fmaf(a6u, l0, dl0);
                dl1 = fmaf(a6u, l1, dl1);
                #pragma unroll
                for (int jj = 0; jj < 4; ++jj) {
                    const float r = rv[u][jj];
                    dr[jj]   = fmaf(a6u, r, dr[jj]);
                    acc0[jj] = fmaf(a4u, fabsf(l0 + r), acc0[jj]);
                    acc1[jj] = fmaf(a4u, fabsf(l1 + r), acc1[jj]);
                }
            }
        }
    }
    __syncthreads();                       // all waves done with Rs -> reuse as xT

    // stage xT[j][w ^ swz(j)] into the dead R buffers (64 KB exactly).
    // swz = ((j>>2)&15)<<1 : write ~2-way (free), read conflict-free, keeps
    // 8B alignment for the v2f reads.
    float* xT = &Rs[0][0];
    {
        const float* xg = x + b * 16384;
        #pragma unroll
        for (int q = 0; q < 16; ++q) {
            const int idx = t + q * 256;
            const int w = idx >> 5, j4 = (idx & 31) * 4;
            const int s = ((j4 >> 2) & 15) << 1;
            const v4f xv = *(const v4f*)(xg + w * 128 + j4);
            xT[(j4 + 0) * 128 + (w ^ s)] = xv[0];
            xT[(j4 + 1) * 128 + (w ^ s)] = xv[1];
            xT[(j4 + 2) * 128 + (w ^ s)] = xv[2];
            xT[(j4 + 3) * 128 + (w ^ s)] = xv[3];
        }
    }

    // softmax over j (row lives in one 32-lane half-wave)
    const int i0r = it * 16 + il0;
    float ev0[4], ev1[4];
    {
        const v4f b0 = *(const v4f*)(bias + (i0r + 0) * 128 + j0);
        const v4f b1 = *(const v4f*)(bias + (i0r + 1) * 128 + j0);
        #pragma unroll
        for (int jj = 0; jj < 4; ++jj) {
            ev0[jj] = acc0[jj] + dl0 + dr[jj] + b0[jj];
            ev1[jj] = acc1[jj] + dl1 + dr[jj] + b1[jj];
        }
    }
#define SOFTMAX_ROW(EV, ROW) do {                                               \
    float m_ = fmaxf(fmaxf(EV[0], EV[1]), fmaxf(EV[2], EV[3]));                 \
    _Pragma("unroll") for (int d_ = 1; d_ <= 16; d_ <<= 1)                      \
        m_ = fmaxf(m_, __shfl_xor(m_, d_));                                     \
    float p0 = __expf(EV[0] - m_), p1 = __expf(EV[1] - m_);                     \
    float p2 = __expf(EV[2] - m_), p3 = __expf(EV[3] - m_);                     \
    float s_ = p0 + p1 + p2 + p3;                                               \
    _Pragma("unroll") for (int d_ = 1; d_ <= 16; d_ <<= 1)                      \
        s_ += __shfl_xor(s_, d_);                                               \
    const float inv_ = 1.f / s_;                                                \
    *(v4f*)&att[(ROW) * 132 + j0] =                                             \
        (v4f){p0 * inv_, p1 * inv_, p2 * inv_, p3 * inv_}; } while (0)

    SOFTMAX_ROW(ev0, il0 + 0);
    SOFTMAX_ROW(ev1, il0 + 1);
    __syncthreads();

    // phase 2: out[b][w][i] = sigmoid(sum_j att[i][j]*x[b][w][j]); lane 2w x 4i
    const int iq2 = t & 3, wp = t >> 2;
    const int i4 = iq2 * 4, w0 = wp * 2;
    float o[2][4] = {};
    #pragma unroll 4
    for (int jc = 0; jc < 32; ++jc) {
        const int wx = w0 ^ ((jc & 15) << 1);
        v4f av[4]; v2f xv[4];
        #pragma unroll
        for (int q = 0; q < 4; ++q)
            av[q] = *(const v4f*)&att[(i4 + q) * 132 + jc * 4];
        #pragma unroll
        for (int u = 0; u < 4; ++u)
            xv[u] = *(const v2f*)&xT[(jc * 4 + u) * 128 + wx];
        #pragma unroll
        for (int u = 0; u < 4; ++u)
            #pragma unroll
            for (int q = 0; q < 4; ++q) {
                o[0][q] = fmaf(xv[u].x, av[q][u], o[0][q]);
                o[1][q] = fmaf(xv[u].y, av[q][u], o[1][q]);
            }
    }
    #pragma unroll
    for (int w = 0; w < 2; ++w) {
        v4f r;
        r[0] = 1.f / (1.f + __expf(-o[w][0]));
        r[1] = 1.f / (1.f + __expf(-o[w][1]));
        r[2] = 1.f / (1.f + __expf(-o[w][2]));
        r[3] = 1.f / (1.f + __expf(-o[w][3]));
        *(v4f*)(out + (size_t)b * 16384 + (w0 + w) * 128 + it * 16 + i4) = r;
    }
}

extern "C" void kernel_launch(void* const* d_in, const int* in_sizes, int n_in,
                              void* d_out, int out_size, void* d_ws, size_t ws_size,
                              hipStream_t stream) {
    const float* x     = (const float*)d_in[0];
    const float* lin_w = (const float*)d_in[1];
    const float* lin_b = (const float*)d_in[2];
    const float* a     = (const float*)d_in[3];
    const float* bias  = (const float*)d_in[4];
    float* ws  = (float*)d_ws;
    float* out = (float*)d_out;

    k_linear<<<dim3(32, 2, 8), 256, 0, stream>>>(x, lin_w, lin_b, a, ws);
    k_attn  <<<dim3(32, 8), 256, 0, stream>>>(x, bias, ws, out);
}